// Round 11
// baseline (192.623 us; speedup 1.0000x reference)
//
#include <hip/hip_runtime.h>

#define B_G   100
#define N_PER 1000
#define E_PER 12000
#define NTOT  (B_G * N_PER)
#define ETOT  (B_G * E_PER)
#define KSEL  800
#define EPT   12

typedef __attribute__((ext_vector_type(8))) short short8;
typedef __attribute__((ext_vector_type(4))) float float4_;

__device__ __forceinline__ unsigned short f2bf(float f) {
    unsigned u = __float_as_uint(f);
    u += 0x7fffu + ((u >> 16) & 1u);          // RNE
    return (unsigned short)(u >> 16);
}
__device__ __forceinline__ float upk(unsigned q) {          // bf16 ew in hi16
    return __uint_as_float(q & 0xFFFF0000u);
}
// fp8 e4m3 (z>=0): raw decode = true_value * 2^-120 (exact, incl subnormals)
__device__ __forceinline__ float dec_raw(unsigned byte7f) { // pass (b&0x7f)
    return __uint_as_float(byte7f << 20);
}
__device__ __forceinline__ unsigned enc_fp8(float z) {      // z >= 0, z < 448
    unsigned u = __float_as_uint(z * 0x1p-120f);
    u += 0x7FFFFu + ((u >> 20) & 1u);                       // RNE at bit 20
    return u >> 20;
}

// ===== whole network, one block per graph; CSR+z in LDS; h2 via global ======
// LDS map (145024 B):
//  [0,64000)    zs: fp8 z rows (64 B, chunk-swizzled); xl f[3000] early
//  [64000)      csr u32[12000]  (bf16 ew <<16 | src)
//  [112000)     ends int[1024]  (inclusive rowptr)
//  [116096)     dl f[1024]      (aliases posc during fill)
//  [120192)     wpart i[16] / x1b f[64]
//  [120448)     uA 16384: aggv f[3000] / keys u64[1024]; sred@12288;
//               red@8192; a1@12288 a2@12544 zb@12672
//  [136832)     w2s bf16[64][64]  (B operand, [n][k])
__global__ __launch_bounds__(1024) void k_all(
    const int* __restrict__ ei, const float* __restrict__ ew,
    const float* __restrict__ x,
    const float* __restrict__ w1, const float* __restrict__ b1,
    const float* __restrict__ w2, const float* __restrict__ b2,
    const float* __restrict__ pw,
    const float* __restrict__ l1w, const float* __restrict__ l1b,
    const float* __restrict__ l2w, const float* __restrict__ l2b,
    const float* __restrict__ l3w, const float* __restrict__ l3b,
    unsigned char* __restrict__ h2g, float* __restrict__ out) {
    __shared__ __align__(16) unsigned char smem[145024];
    unsigned char* zs = smem;
    float* xl = (float*)smem;
    unsigned* csr = (unsigned*)(smem + 64000);
    int*   ends = (int*)(smem + 112000);
    float* dl   = (float*)(smem + 116096);
    int*   posc = (int*)(smem + 116096);         // alias, dead before dl
    int*   wpart = (int*)(smem + 120192);
    float* x1b   = (float*)(smem + 120192);
    unsigned char* uA = smem + 120448;
    float* aggv = (float*)uA;
    unsigned short* w2s = (unsigned short*)(smem + 136832);

    int b = blockIdx.x, tid = threadIdx.x;
    int wid = tid >> 6, lane = tid & 63;
    int gbase = b * N_PER, ebase = b * E_PER;

    // ---- phase 0: edges into regs, xl load, w2 -> bf16 LDS, init ----
    int esrc[EPT], edst[EPT]; float eww[EPT];
    int ne = (tid < (E_PER - (EPT - 1) * 1024)) ? EPT : EPT - 1;
#pragma unroll
    for (int i = 0; i < EPT; i++) {
        if (i < ne) {
            int e = tid + i * 1024;
            esrc[i] = ei[ebase + e] - gbase;
            edst[i] = ei[ETOT + ebase + e] - gbase;
            eww[i]  = ew[ebase + e];
        }
    }
    ends[tid] = 0;
    for (int i = tid; i < N_PER * 3; i += 1024) xl[i] = x[(size_t)gbase * 3 + i];
    {   // w2s[n*64+k] = bf16(w2[k][n])
        int n = tid >> 4;
        for (int k = (tid & 15) * 4, ke = k + 4; k < ke; k++)
            w2s[n * 64 + k] = f2bf(w2[k * 64 + n]);
    }
    __syncthreads();
    // ---- count ----
#pragma unroll
    for (int i = 0; i < EPT; i++)
        if (i < ne) atomicAdd(&ends[edst[i]], 1);
    __syncthreads();
    // ---- shuffle inclusive scan ----
    int v = ends[tid];
    int sc = v;
#pragma unroll
    for (int m = 1; m < 64; m <<= 1) {
        int t = __shfl_up(sc, m);
        if (lane >= m) sc += t;
    }
    if (lane == 63) wpart[wid] = sc;
    __syncthreads();
    if (tid < 16) {
        int s2 = wpart[tid];
#pragma unroll
        for (int m = 1; m < 16; m <<= 1) {
            int t = __shfl_up(s2, m);
            if (tid >= m) s2 += t;
        }
        wpart[tid] = s2;
    }
    __syncthreads();
    int incl = sc + (wid > 0 ? wpart[wid - 1] : 0);
    ends[tid] = incl;
    posc[tid] = incl - v;
    __syncthreads();
    // ---- CSR fill into LDS ----
#pragma unroll
    for (int i = 0; i < EPT; i++)
        if (i < ne) {
            int p = atomicAdd(&posc[edst[i]], 1);
            csr[p] = ((unsigned)f2bf(eww[i]) << 16) | (unsigned)esrc[i];
        }
    __syncthreads();
    // ---- wsum (LDS csr) -> dl; y = dl*x in place ----
    float dmy = 0.f;
    int s0i = 0, e0i = 0;
    if (tid < N_PER) {
        s0i = tid ? ends[tid - 1] : 0;
        e0i = ends[tid];
        float s0 = 0.f, s1 = 0.f;
        int k = s0i;
        for (; k + 2 <= e0i; k += 2) { s0 += upk(csr[k]); s1 += upk(csr[k + 1]); }
        if (k < e0i) s0 += upk(csr[k]);
        dmy = rsqrtf(s0 + s1 + 1.0f);
        dl[tid] = dmy;                            // posc dead (fill barrier above)
        xl[tid * 3 + 0] *= dmy;
        xl[tid * 3 + 1] *= dmy;
        xl[tid * 3 + 2] *= dmy;
    }
    __syncthreads();
    // ---- conv1 gather: agg = dl[dst]*(y[dst] + sum ew*y[src]) ----
    if (tid < N_PER) {
        float a0 = xl[tid * 3 + 0], a1 = xl[tid * 3 + 1], a2 = xl[tid * 3 + 2];
        for (int k = s0i; k < e0i; k++) {
            unsigned q = csr[k];
            int i0 = (int)(q & 0xFFFFu) * 3;
            float wv = upk(q);
            a0 += wv * xl[i0]; a1 += wv * xl[i0 + 1]; a2 += wv * xl[i0 + 2];
        }
        aggv[tid * 3 + 0] = dmy * a0;
        aggv[tid * 3 + 1] = dmy * a1;
        aggv[tid * 3 + 2] = dmy * a2;
    }
    __syncthreads();
    // ---- W1: h1 = relu(agg@W1+b1); z = dl*h1 -> fp8 swizzled; x1 partials ---
    {
        float w0 = w1[lane], w1v = w1[64 + lane], w2v = w1[128 + lane], bf = b1[lane];
        float* sred = (float*)(uA + 12288);
        float px = 0.f;
        int chunk = (lane & 31) >> 3;
        int word  = ((lane >= 32) ? 2 : 0) + ((lane & 7) >> 2);
        for (int node = wid; node < N_PER; node += 16) {
            float a0 = aggv[node * 3], a1 = aggv[node * 3 + 1], a2 = aggv[node * 3 + 2];
            float hv = fmaxf(a0 * w0 + a1 * w1v + a2 * w2v + bf, 0.f);
            px += hv;
            unsigned byte = enc_fp8(dl[node] * hv);
            unsigned t1 = __shfl_xor(byte, 1);
            unsigned v16 = (lane & 1) ? (t1 | (byte << 8)) : (byte | (t1 << 8));
            unsigned t2 = __shfl_xor(v16, 2);
            unsigned v32 = (lane & 2) ? (t2 | (v16 << 16)) : (v16 | (t2 << 16));
            if ((lane & 3) == 0) {
                int cs = chunk ^ ((node >> 1) & 3);
                *(unsigned*)(zs + node * 64 + cs * 16 + word * 4) = v32;
            }
        }
        sred[wid * 64 + lane] = px;
        __syncthreads();                          // zs + sred complete; aggv dead
        if (tid < 64) {
            float t = 0.f;
            for (int r = 0; r < 16; r++) t += sred[r * 64 + tid];
            x1b[tid] = t * (1.0f / N_PER);
        }
    }
    // ---- conv2: per-tile fused agg -> MFMA -> epilogue (h2 to GLOBAL) ------
    // #pragma unroll 1 on the tile loop keeps only ONE tile's registers live:
    // peak ~ acc[16] / (Af8 + Bf32 + accv16) < 64 VGPR -> no scratch spills.
    int kgrp = lane >> 4, nloc = lane & 15;
    unsigned long long* keys = (unsigned long long*)uA;
    if (tid >= N_PER) keys[tid] = 0ull;           // pad entries sort last
    float b2c[4], pwc[4];
#pragma unroll
    for (int c = 0; c < 4; ++c) {
        b2c[c] = b2[c * 16 + nloc];
        pwc[c] = pw[c * 16 + nloc];
    }
    float invn;
    {
        float p = pw[lane], pn = p * p;
#pragma unroll
        for (int m = 32; m; m >>= 1) pn += __shfl_xor(pn, m);
        invn = rsqrtf(pn);
    }
#pragma unroll 1
    for (int ti = 0; ti < 4; ti++) {
        int t = wid + ti * 16;
        if (t >= 63) continue;                    // tiles 0..62 cover 1000 nodes
        int li = t * 16 + nloc;
        bool valid = li < N_PER;
        float acc[16];
        int s = 0, cn = 0;
        if (valid) {
            uint4 rv = *(const uint4*)(zs + li * 64 + ((kgrp ^ ((li >> 1) & 3)) << 4));
#pragma unroll
            for (int j = 0; j < 4; j++) {
                acc[j]      = dec_raw((rv.x >> (8 * j)) & 0x7Fu);
                acc[4 + j]  = dec_raw((rv.y >> (8 * j)) & 0x7Fu);
                acc[8 + j]  = dec_raw((rv.z >> (8 * j)) & 0x7Fu);
                acc[12 + j] = dec_raw((rv.w >> (8 * j)) & 0x7Fu);
            }
            s = li ? ends[li - 1] : 0;
            cn = ends[li] - s;
        } else {
#pragma unroll
            for (int j = 0; j < 16; j++) acc[j] = 0.f;
        }
        int mx = cn;
#pragma unroll
        for (int m = 1; m < 16; m <<= 1) mx = max(mx, __shfl_xor(mx, m));
        for (int k = 0; k < mx; k++) {
            if (k < cn) {
                unsigned q = csr[s + k];
                int src = (int)(q & 0xFFFFu);
                float wv = upk(q);
                uint4 rv = *(const uint4*)(zs + src * 64 + ((kgrp ^ ((src >> 1) & 3)) << 4));
#pragma unroll
                for (int j = 0; j < 4; j++) {
                    acc[j]      += wv * dec_raw((rv.x >> (8 * j)) & 0x7Fu);
                    acc[4 + j]  += wv * dec_raw((rv.y >> (8 * j)) & 0x7Fu);
                    acc[8 + j]  += wv * dec_raw((rv.z >> (8 * j)) & 0x7Fu);
                    acc[12 + j] += wv * dec_raw((rv.w >> (8 * j)) & 0x7Fu);
                }
            }
        }
        float scale = (valid ? dl[li] : 0.f) * 0x1p120f;
        short8 Af0, Af1;
#pragma unroll
        for (int j = 0; j < 8; j++) {
            Af0[j] = (short)f2bf(scale * acc[j]);      // feats kgrp*8+j
            Af1[j] = (short)f2bf(scale * acc[8 + j]);  // feats 32+kgrp*8+j
        }
        // B fragments from LDS (w2s [n][k]); MFMA; epilogue
        float4_ accv[4];
#pragma unroll
        for (int c = 0; c < 4; ++c) {
            const short8* bp = (const short8*)(w2s + (c * 16 + nloc) * 64 + kgrp * 8);
            accv[c] = __builtin_amdgcn_mfma_f32_16x16x32_bf16(Af0, bp[0], (float4_){0.f,0.f,0.f,0.f}, 0, 0, 0);
            accv[c] = __builtin_amdgcn_mfma_f32_16x16x32_bf16(Af1, bp[4], accv[c], 0, 0, 0);
        }
#pragma unroll
        for (int r2 = 0; r2 < 4; ++r2) {
            int li2 = t * 16 + kgrp * 4 + r2;     // C layout: row=(lane>>4)*4+reg
            bool valid2 = li2 < N_PER;
            float sp = 0.f;
            unsigned pack = 0;
#pragma unroll
            for (int c = 0; c < 4; ++c) {
                float hv = fmaxf(accv[c][r2] + b2c[c], 0.f);
                sp += hv * pwc[c];
                pack |= enc_fp8(hv) << (8 * c);
            }
            if (valid2)                            // h2[node*64 + nloc*4 + c]
                *(unsigned*)(h2g + (size_t)(gbase + li2) * 64 + nloc * 4) = pack;
#pragma unroll
            for (int m = 1; m < 16; m <<= 1) sp += __shfl_xor(sp, m);
            if (valid2 && nloc == 0) {
                float scv = tanhf(sp * invn);
                unsigned bits = __float_as_uint(scv);
                unsigned u = (bits & 0x80000000u) ? ~bits : (bits | 0x80000000u);
                keys[li2] = ((unsigned long long)u << 32) | (unsigned)(1023 - li2);
            }
        }
    }
    __syncthreads();
    // ---- hybrid bitonic sort: j<64 via shfl, j>=64 via LDS ----
    {
        unsigned long long key = keys[tid];
        for (int k = 2; k <= 1024; k <<= 1) {
            for (int j = k >> 1; j > 0; j >>= 1) {
                bool desc = (tid & k) == 0;
                unsigned long long p;
                if (j >= 64) {
                    keys[tid] = key;
                    __syncthreads();
                    p = keys[tid ^ j];
                    __syncthreads();
                } else {
                    p = __shfl_xor(key, j);
                }
                bool low = (tid & j) == 0;
                bool sw = low ? (desc ? (key < p) : (key > p))
                              : (desc ? (p < key) : (p > key));
                if (sw) key = p;
            }
        }
        keys[tid] = key;
    }
    __syncthreads();
    // ---- weighted mean over top-K (h2 from L2-hot global) + MLP ----
    float* red   = (float*)(uA + 8192);
    float* a1buf = (float*)(uA + 12288);
    float* a2buf = (float*)(uA + 12544);
    float* zbuf  = (float*)(uA + 12672);
    {
        int f = tid & 63, w16 = tid >> 6;
        int boff = ((f & 15) << 2) + (f >> 4);    // node*64 + (f&15)*4 + (f>>4)
        float acc2 = 0.f;
        for (int r = w16; r < KSEL; r += 16) {
            unsigned long long key = keys[r];
            int idx = 1023 - (int)(key & 0xFFFFFFFFu);
            unsigned u = (unsigned)(key >> 32);
            unsigned bits = (u & 0x80000000u) ? (u & 0x7FFFFFFFu) : ~u;
            float valS = __uint_as_float(bits) * 0x1p120f;
            acc2 += valS * dec_raw((unsigned)h2g[(size_t)(gbase + idx) * 64 + boff] & 0x7Fu);
        }
        red[tid] = acc2;
    }
    __syncthreads();
    if (tid < 64) {
        float s2 = 0.f;
        for (int ww = 0; ww < 16; ww++) s2 += red[ww * 64 + tid];
        zbuf[tid] = x1b[tid] + s2 * (1.0f / KSEL);
    }
    __syncthreads();
    if (tid < 64) {
        float a = l1b[tid];
        for (int k = 0; k < 64; k++) a += zbuf[k] * l1w[k * 64 + tid];
        a1buf[tid] = fmaxf(a, 0.f);
    }
    __syncthreads();
    if (tid < 32) {
        float a = l2b[tid];
        for (int k = 0; k < 64; k++) a += a1buf[k] * l2w[k * 32 + tid];
        a2buf[tid] = fmaxf(a, 0.f);
    }
    __syncthreads();
    if (tid == 0) {
        float t = l3b[0];
        for (int k = 0; k < 32; k++) t += a2buf[k] * l3w[k];
        out[b] = 1.0f / (1.0f + expf(-t));
    }
}

extern "C" void kernel_launch(void* const* d_in, const int* in_sizes, int n_in,
                              void* d_out, int out_size, void* d_ws, size_t ws_size,
                              hipStream_t stream) {
    const float* x   = (const float*)d_in[0];
    const int*   ei  = (const int*)d_in[1];
    const float* ew  = (const float*)d_in[2];
    const float* c1w = (const float*)d_in[4];
    const float* c1b = (const float*)d_in[5];
    const float* c2w = (const float*)d_in[6];
    const float* c2b = (const float*)d_in[7];
    const float* pw  = (const float*)d_in[8];
    const float* l1w = (const float*)d_in[9];
    const float* l1b = (const float*)d_in[10];
    const float* l2w = (const float*)d_in[11];
    const float* l2b = (const float*)d_in[12];
    const float* l3w = (const float*)d_in[13];
    const float* l3b = (const float*)d_in[14];
    float* out = (float*)d_out;
    unsigned char* h2g = (unsigned char*)d_ws;
    (void)ws_size; (void)in_sizes; (void)n_in; (void)out_size;

    k_all<<<B_G, 1024, 0, stream>>>(ei, ew, x, c1w, c1b, c2w, c2b, pw,
                                    l1w, l1b, l2w, l2b, l3w, l3b, h2g, out);
}

// Round 12
// 189.746 us; speedup vs baseline: 1.0152x; 1.0152x over previous
//
#include <hip/hip_runtime.h>

#define B_G   100
#define N_PER 1000
#define E_PER 12000
#define NTOT  (B_G * N_PER)
#define ETOT  (B_G * E_PER)
#define KSEL  800
#define EPT   12
#define NH    500            // nodes per conv2 half-block
#define HCAP  8192           // LDS csr-slice capacity (entries)

typedef __attribute__((ext_vector_type(8))) short short8;
typedef __attribute__((ext_vector_type(4))) float float4_;

__device__ __forceinline__ unsigned short f2bf(float f) {
    unsigned u = __float_as_uint(f);
    u += 0x7fffu + ((u >> 16) & 1u);          // RNE
    return (unsigned short)(u >> 16);
}
__device__ __forceinline__ float upk(unsigned q) {          // bf16 ew in hi16
    return __uint_as_float(q & 0xFFFF0000u);
}
// fp8 e4m3 (z>=0): raw decode = true_value * 2^-120 (exact, incl subnormals)
__device__ __forceinline__ float dec_raw(unsigned byte7f) {
    return __uint_as_float(byte7f << 20);
}
__device__ __forceinline__ unsigned enc_fp8(float z) {
    unsigned u = __float_as_uint(z * 0x1p-120f);
    u += 0x7FFFFu + ((u >> 20) & 1u);
    return u >> 20;
}

// ===== K1: histogram + scan + CSR fill (LDS) + dl; dump to global ===========
__global__ __launch_bounds__(1024) void k1_build(
    const int* __restrict__ ei, const float* __restrict__ ew,
    unsigned* __restrict__ csr_g, int* __restrict__ ends_g,
    float* __restrict__ dl_g) {
    __shared__ unsigned csr[E_PER];
    __shared__ int ends[1024];
    __shared__ int posc[1024];
    __shared__ int wpart[16];
    int b = blockIdx.x, tid = threadIdx.x;
    int wid = tid >> 6, lane = tid & 63;
    int gbase = b * N_PER, ebase = b * E_PER;

    int esrc[EPT], edst[EPT]; float eww[EPT];
    int ne = (tid < (E_PER - (EPT - 1) * 1024)) ? EPT : EPT - 1;
#pragma unroll
    for (int i = 0; i < EPT; i++) {
        if (i < ne) {
            int e = tid + i * 1024;
            esrc[i] = ei[ebase + e] - gbase;
            edst[i] = ei[ETOT + ebase + e] - gbase;
            eww[i]  = ew[ebase + e];
        }
    }
    ends[tid] = 0;
    __syncthreads();
#pragma unroll
    for (int i = 0; i < EPT; i++)
        if (i < ne) atomicAdd(&ends[edst[i]], 1);
    __syncthreads();
    int v = ends[tid], sc = v;
#pragma unroll
    for (int m = 1; m < 64; m <<= 1) {
        int t = __shfl_up(sc, m);
        if (lane >= m) sc += t;
    }
    if (lane == 63) wpart[wid] = sc;
    __syncthreads();
    if (tid < 16) {
        int s2 = wpart[tid];
#pragma unroll
        for (int m = 1; m < 16; m <<= 1) {
            int t = __shfl_up(s2, m);
            if (tid >= m) s2 += t;
        }
        wpart[tid] = s2;
    }
    __syncthreads();
    int incl = sc + (wid > 0 ? wpart[wid - 1] : 0);
    ends[tid] = incl;
    posc[tid] = incl - v;
    __syncthreads();
#pragma unroll
    for (int i = 0; i < EPT; i++)
        if (i < ne) {
            int p = atomicAdd(&posc[edst[i]], 1);
            csr[p] = ((unsigned)f2bf(eww[i]) << 16) | (unsigned)esrc[i];
        }
    __syncthreads();
    if (tid < N_PER) {
        int s = tid ? ends[tid - 1] : 0, e = ends[tid];
        float s0 = 0.f, s1 = 0.f;
        int k = s;
        for (; k + 2 <= e; k += 2) { s0 += upk(csr[k]); s1 += upk(csr[k + 1]); }
        if (k < e) s0 += upk(csr[k]);
        dl_g[gbase + tid] = rsqrtf(s0 + s1 + 1.0f);
        ends_g[gbase + tid] = e;
    }
    for (int i = tid; i < E_PER; i += 1024)
        csr_g[(size_t)ebase + i] = csr[i];
}

// ===== K2: conv1 gather + W1 + fp8-z (global) + x1 ==========================
__global__ __launch_bounds__(1024) void k2_conv1(
    const float* __restrict__ x,
    const float* __restrict__ w1, const float* __restrict__ b1,
    const unsigned* __restrict__ csr_g, const int* __restrict__ ends_g,
    const float* __restrict__ dl_g,
    unsigned char* __restrict__ zg, float* __restrict__ x1g) {
    __shared__ float xl[3000];
    __shared__ unsigned csr[E_PER];
    __shared__ int ends[1024];
    __shared__ float dl[1024];
    __shared__ float aggv[3000];
    __shared__ float sred[1024];
    int b = blockIdx.x, tid = threadIdx.x;
    int wid = tid >> 6, lane = tid & 63;
    int gbase = b * N_PER, ebase = b * E_PER;

    for (int i = tid; i < N_PER * 3; i += 1024) xl[i] = x[(size_t)gbase * 3 + i];
    for (int i = tid; i < E_PER; i += 1024) csr[i] = csr_g[(size_t)ebase + i];
    if (tid < N_PER) {
        ends[tid] = ends_g[gbase + tid];
        dl[tid] = dl_g[gbase + tid];
    }
    __syncthreads();
    if (tid < N_PER) {
        float d = dl[tid];
        xl[tid * 3 + 0] *= d; xl[tid * 3 + 1] *= d; xl[tid * 3 + 2] *= d;
    }
    __syncthreads();
    if (tid < N_PER) {
        int s = tid ? ends[tid - 1] : 0, e = ends[tid];
        float a0 = xl[tid * 3 + 0], a1 = xl[tid * 3 + 1], a2 = xl[tid * 3 + 2];
        for (int k = s; k < e; k++) {
            unsigned q = csr[k];
            int i0 = (int)(q & 0xFFFFu) * 3;
            float wv = upk(q);
            a0 += wv * xl[i0]; a1 += wv * xl[i0 + 1]; a2 += wv * xl[i0 + 2];
        }
        float d = dl[tid];
        aggv[tid * 3 + 0] = d * a0;
        aggv[tid * 3 + 1] = d * a1;
        aggv[tid * 3 + 2] = d * a2;
    }
    __syncthreads();
    {
        float w0 = w1[lane], w1v = w1[64 + lane], w2v = w1[128 + lane], bf = b1[lane];
        float px = 0.f;
        int chunk = (lane & 31) >> 3;
        int word  = ((lane >= 32) ? 2 : 0) + ((lane & 7) >> 2);
        unsigned char* zrow = zg + (size_t)b * 64000;
        for (int node = wid; node < N_PER; node += 16) {
            float a0 = aggv[node * 3], a1 = aggv[node * 3 + 1], a2 = aggv[node * 3 + 2];
            float hv = fmaxf(a0 * w0 + a1 * w1v + a2 * w2v + bf, 0.f);
            px += hv;
            unsigned byte = enc_fp8(dl[node] * hv);
            unsigned t1 = __shfl_xor(byte, 1);
            unsigned v16 = (lane & 1) ? (t1 | (byte << 8)) : (byte | (t1 << 8));
            unsigned t2 = __shfl_xor(v16, 2);
            unsigned v32 = (lane & 2) ? (t2 | (v16 << 16)) : (v16 | (t2 << 16));
            if ((lane & 3) == 0) {
                int cs = chunk ^ ((node >> 1) & 3);
                *(unsigned*)(zrow + node * 64 + cs * 16 + word * 4) = v32;
            }
        }
        sred[wid * 64 + lane] = px;
        __syncthreads();
        if (tid < 64) {
            float t = 0.f;
            for (int r = 0; r < 16; r++) t += sred[r * 64 + tid];
            x1g[b * 64 + tid] = t * (1.0f / N_PER);
        }
    }
}

// ===== K3: conv2 agg (z LDS) + MFMA + epilogue; 2 blocks/graph ==============
__global__ __launch_bounds__(1024) void k3_conv2(
    const unsigned char* __restrict__ zg, const unsigned* __restrict__ csr_g,
    const int* __restrict__ ends_g, const float* __restrict__ dl_g,
    const float* __restrict__ w2, const float* __restrict__ b2,
    const float* __restrict__ pw,
    unsigned char* __restrict__ h2g, float* __restrict__ score_g) {
    __shared__ __align__(16) unsigned char zs[64000];
    __shared__ unsigned csr[HCAP];
    __shared__ int ends[NH + 12];
    __shared__ float dl[NH + 12];
    __shared__ unsigned short w2s[64 * 64];
    int blk = blockIdx.x;
    int g = blk >> 1, h = blk & 1;
    int tid = threadIdx.x, wid = tid >> 6, lane = tid & 63;
    int kgrp = lane >> 4, nloc = lane & 15;
    int gbase = g * N_PER, nbase = h * NH;

    for (int i = tid; i < 64000 / 4; i += 1024)
        ((unsigned*)zs)[i] = ((const unsigned*)(zg + (size_t)g * 64000))[i];
    int base = h ? ends_g[gbase + NH - 1] : 0;
    int etot = ends_g[gbase + nbase + NH - 1];
    int nE = etot - base;
    if (tid < NH) {
        ends[tid] = ends_g[gbase + nbase + tid] - base;
        dl[tid] = dl_g[gbase + nbase + tid];
    }
    for (int i = tid; i < nE; i += 1024)
        csr[i] = csr_g[(size_t)g * E_PER + base + i];
    {   // w2s[n*64+k] = bf16(w2[k][n])
        int n = tid >> 4;
        for (int k = (tid & 15) * 4, ke = k + 4; k < ke; k++)
            w2s[n * 64 + k] = f2bf(w2[k * 64 + n]);
    }
    float b2c[4], pwc[4];
#pragma unroll
    for (int c = 0; c < 4; ++c) {
        b2c[c] = b2[c * 16 + nloc];
        pwc[c] = pw[c * 16 + nloc];
    }
    float invn;
    {
        float p = pw[lane], pn = p * p;
#pragma unroll
        for (int m = 32; m; m >>= 1) pn += __shfl_xor(pn, m);
        invn = rsqrtf(pn);
    }
    __syncthreads();
#pragma unroll 1
    for (int ti = 0; ti < 2; ti++) {              // 32 tiles cover 500 nodes
        int t = wid + ti * 16;
        int li = t * 16 + nloc;                   // local node in half
        bool valid = li < NH;
        float acc[16];
        int s = 0, cn = 0;
        if (valid) {
            int gn = nbase + li;                  // graph-local node
            uint4 rv = *(const uint4*)(zs + gn * 64 + ((kgrp ^ ((gn >> 1) & 3)) << 4));
#pragma unroll
            for (int j = 0; j < 4; j++) {
                acc[j]      = dec_raw((rv.x >> (8 * j)) & 0x7Fu);
                acc[4 + j]  = dec_raw((rv.y >> (8 * j)) & 0x7Fu);
                acc[8 + j]  = dec_raw((rv.z >> (8 * j)) & 0x7Fu);
                acc[12 + j] = dec_raw((rv.w >> (8 * j)) & 0x7Fu);
            }
            s = li ? ends[li - 1] : 0;
            cn = ends[li] - s;
        } else {
#pragma unroll
            for (int j = 0; j < 16; j++) acc[j] = 0.f;
        }
        int mx = cn;
#pragma unroll
        for (int m = 1; m < 16; m <<= 1) mx = max(mx, __shfl_xor(mx, m));
        for (int k = 0; k < mx; k++) {
            if (k < cn) {
                unsigned q = csr[s + k];
                int src = (int)(q & 0xFFFFu);
                float wv = upk(q);
                uint4 rv = *(const uint4*)(zs + src * 64 + ((kgrp ^ ((src >> 1) & 3)) << 4));
#pragma unroll
                for (int j = 0; j < 4; j++) {
                    acc[j]      += wv * dec_raw((rv.x >> (8 * j)) & 0x7Fu);
                    acc[4 + j]  += wv * dec_raw((rv.y >> (8 * j)) & 0x7Fu);
                    acc[8 + j]  += wv * dec_raw((rv.z >> (8 * j)) & 0x7Fu);
                    acc[12 + j] += wv * dec_raw((rv.w >> (8 * j)) & 0x7Fu);
                }
            }
        }
        float scale = (valid ? dl[li] : 0.f) * 0x1p120f;
        short8 Af0, Af1;
#pragma unroll
        for (int j = 0; j < 8; j++) {
            Af0[j] = (short)f2bf(scale * acc[j]);
            Af1[j] = (short)f2bf(scale * acc[8 + j]);
        }
        float4_ accv[4];
#pragma unroll
        for (int c = 0; c < 4; ++c) {
            const short8* bp = (const short8*)(w2s + (c * 16 + nloc) * 64 + kgrp * 8);
            accv[c] = __builtin_amdgcn_mfma_f32_16x16x32_bf16(Af0, bp[0], (float4_){0.f,0.f,0.f,0.f}, 0, 0, 0);
            accv[c] = __builtin_amdgcn_mfma_f32_16x16x32_bf16(Af1, bp[4], accv[c], 0, 0, 0);
        }
#pragma unroll
        for (int r2 = 0; r2 < 4; ++r2) {
            int li2 = t * 16 + kgrp * 4 + r2;     // C layout: row=(lane>>4)*4+reg
            bool valid2 = li2 < NH;
            float sp = 0.f;
            unsigned pack = 0;
#pragma unroll
            for (int c = 0; c < 4; ++c) {
                float hv = fmaxf(accv[c][r2] + b2c[c], 0.f);
                sp += hv * pwc[c];
                pack |= enc_fp8(hv) << (8 * c);
            }
            if (valid2)
                *(unsigned*)(h2g + (size_t)(gbase + nbase + li2) * 64 + nloc * 4) = pack;
#pragma unroll
            for (int m = 1; m < 16; m <<= 1) sp += __shfl_xor(sp, m);
            if (valid2 && nloc == 0)
                score_g[gbase + nbase + li2] = tanhf(sp * invn);
        }
    }
}

// ===== K4: topk sort + pooled mean + MLP + sigmoid ==========================
__global__ __launch_bounds__(1024) void k4_topk(
    const float* __restrict__ score_g, const unsigned char* __restrict__ h2g,
    const float* __restrict__ x1g,
    const float* __restrict__ l1w, const float* __restrict__ l1b,
    const float* __restrict__ l2w, const float* __restrict__ l2b,
    const float* __restrict__ l3w, const float* __restrict__ l3b,
    float* __restrict__ out) {
    __shared__ unsigned long long keys[1024];
    __shared__ float red[1024];
    __shared__ float zbuf[64], a1buf[64], a2buf[32];
    int b = blockIdx.x, tid = threadIdx.x;
    if (tid < N_PER) {
        float scv = score_g[b * N_PER + tid];
        unsigned bits = __float_as_uint(scv);
        unsigned u = (bits & 0x80000000u) ? ~bits : (bits | 0x80000000u);
        keys[tid] = ((unsigned long long)u << 32) | (unsigned)(1023 - tid);
    } else {
        keys[tid] = 0ull;
    }
    __syncthreads();
    {
        unsigned long long key = keys[tid];
        for (int k = 2; k <= 1024; k <<= 1) {
            for (int j = k >> 1; j > 0; j >>= 1) {
                bool desc = (tid & k) == 0;
                unsigned long long p;
                if (j >= 64) {
                    keys[tid] = key;
                    __syncthreads();
                    p = keys[tid ^ j];
                    __syncthreads();
                } else {
                    p = __shfl_xor(key, j);
                }
                bool low = (tid & j) == 0;
                bool sw = low ? (desc ? (key < p) : (key > p))
                              : (desc ? (p < key) : (p > key));
                if (sw) key = p;
            }
        }
        keys[tid] = key;
    }
    __syncthreads();
    {
        int f = tid & 63, w16 = tid >> 6;
        int boff = ((f & 15) << 2) + (f >> 4);
        float acc2 = 0.f;
        for (int r = w16; r < KSEL; r += 16) {
            unsigned long long key = keys[r];
            int idx = 1023 - (int)(key & 0xFFFFFFFFu);
            unsigned u = (unsigned)(key >> 32);
            unsigned bits = (u & 0x80000000u) ? (u & 0x7FFFFFFFu) : ~u;
            float valS = __uint_as_float(bits) * 0x1p120f;
            acc2 += valS * dec_raw((unsigned)h2g[(size_t)(b * N_PER + idx) * 64 + boff] & 0x7Fu);
        }
        red[tid] = acc2;
    }
    __syncthreads();
    if (tid < 64) {
        float s2 = 0.f;
        for (int ww = 0; ww < 16; ww++) s2 += red[ww * 64 + tid];
        zbuf[tid] = x1g[b * 64 + tid] + s2 * (1.0f / KSEL);
    }
    __syncthreads();
    if (tid < 64) {
        float a = l1b[tid];
        for (int k = 0; k < 64; k++) a += zbuf[k] * l1w[k * 64 + tid];
        a1buf[tid] = fmaxf(a, 0.f);
    }
    __syncthreads();
    if (tid < 32) {
        float a = l2b[tid];
        for (int k = 0; k < 64; k++) a += a1buf[k] * l2w[k * 32 + tid];
        a2buf[tid] = fmaxf(a, 0.f);
    }
    __syncthreads();
    if (tid == 0) {
        float t = l3b[0];
        for (int k = 0; k < 32; k++) t += a2buf[k] * l3w[k];
        out[b] = 1.0f / (1.0f + expf(-t));
    }
}

extern "C" void kernel_launch(void* const* d_in, const int* in_sizes, int n_in,
                              void* d_out, int out_size, void* d_ws, size_t ws_size,
                              hipStream_t stream) {
    const float* x   = (const float*)d_in[0];
    const int*   ei  = (const int*)d_in[1];
    const float* ew  = (const float*)d_in[2];
    const float* c1w = (const float*)d_in[4];
    const float* c1b = (const float*)d_in[5];
    const float* c2w = (const float*)d_in[6];
    const float* c2b = (const float*)d_in[7];
    const float* pw  = (const float*)d_in[8];
    const float* l1w = (const float*)d_in[9];
    const float* l1b = (const float*)d_in[10];
    const float* l2w = (const float*)d_in[11];
    const float* l2b = (const float*)d_in[12];
    const float* l3w = (const float*)d_in[13];
    const float* l3b = (const float*)d_in[14];
    float* out = (float*)d_out;

    char* ws = (char*)d_ws;
    size_t o = 0;
    auto alloc = [&](size_t bytes) { size_t cur = o; o += (bytes + 511) & ~(size_t)511; return cur; };
    unsigned*      csr_g   = (unsigned*)(ws + alloc((size_t)ETOT * 4));       // 4.8 MB
    unsigned char* zg      = (unsigned char*)(ws + alloc((size_t)NTOT * 64)); // 6.4 MB
    unsigned char* h2g     = (unsigned char*)(ws + alloc((size_t)NTOT * 64)); // 6.4 MB
    int*           ends_g  = (int*)(ws + alloc((size_t)NTOT * 4));
    float*         dl_g    = (float*)(ws + alloc((size_t)NTOT * 4));
    float*         score_g = (float*)(ws + alloc((size_t)NTOT * 4));
    float*         x1g     = (float*)(ws + alloc((size_t)B_G * 64 * 4));
    (void)ws_size; (void)in_sizes; (void)n_in; (void)out_size;

    k1_build<<<B_G, 1024, 0, stream>>>(ei, ew, csr_g, ends_g, dl_g);
    k2_conv1<<<B_G, 1024, 0, stream>>>(x, c1w, c1b, csr_g, ends_g, dl_g, zg, x1g);
    k3_conv2<<<B_G * 2, 1024, 0, stream>>>(zg, csr_g, ends_g, dl_g, c2w, c2b, pw, h2g, score_g);
    k4_topk <<<B_G, 1024, 0, stream>>>(score_g, h2g, x1g, l1w, l1b, l2w, l2b, l3w, l3b, out);
}

// Round 13
// 186.332 us; speedup vs baseline: 1.0338x; 1.0183x over previous
//
#include <hip/hip_runtime.h>

#define B_G   100
#define N_PER 1000
#define E_PER 12000
#define NTOT  (B_G * N_PER)
#define ETOT  (B_G * E_PER)
#define KSEL  800
#define EPT   12
#define NH    500            // nodes per conv2 half-block
#define HCAP  8192           // LDS csr-slice capacity (entries)

typedef __attribute__((ext_vector_type(8))) short short8;
typedef __attribute__((ext_vector_type(4))) float float4_;

__device__ __forceinline__ unsigned short f2bf(float f) {
    unsigned u = __float_as_uint(f);
    u += 0x7fffu + ((u >> 16) & 1u);          // RNE
    return (unsigned short)(u >> 16);
}
__device__ __forceinline__ float upk(unsigned q) {          // bf16 ew in hi16
    return __uint_as_float(q & 0xFFFF0000u);
}
// fp8 e4m3 (z>=0): raw decode = true_value * 2^-120 (exact, incl subnormals)
__device__ __forceinline__ float dec_raw(unsigned byte7f) {
    return __uint_as_float(byte7f << 20);
}
__device__ __forceinline__ unsigned enc_fp8(float z) {
    unsigned u = __float_as_uint(z * 0x1p-120f);
    u += 0x7FFFFu + ((u >> 20) & 1u);
    return u >> 20;
}

// ===== K1: histogram + scan + CSR fill (LDS) + dl; dump to global ===========
__global__ __launch_bounds__(1024) void k1_build(
    const int* __restrict__ ei, const float* __restrict__ ew,
    unsigned* __restrict__ csr_g, int* __restrict__ ends_g,
    float* __restrict__ dl_g, float* __restrict__ x1g) {
    __shared__ unsigned csr[E_PER];
    __shared__ int ends[1024];
    __shared__ int posc[1024];
    __shared__ int wpart[16];
    int b = blockIdx.x, tid = threadIdx.x;
    int wid = tid >> 6, lane = tid & 63;
    int gbase = b * N_PER, ebase = b * E_PER;

    int esrc[EPT], edst[EPT]; float eww[EPT];
    int ne = (tid < (E_PER - (EPT - 1) * 1024)) ? EPT : EPT - 1;
#pragma unroll
    for (int i = 0; i < EPT; i++) {
        if (i < ne) {
            int e = tid + i * 1024;
            esrc[i] = ei[ebase + e] - gbase;
            edst[i] = ei[ETOT + ebase + e] - gbase;
            eww[i]  = ew[ebase + e];
        }
    }
    ends[tid] = 0;
    if (tid < 64) x1g[b * 64 + tid] = 0.f;       // k2 accumulates via atomics
    __syncthreads();
#pragma unroll
    for (int i = 0; i < EPT; i++)
        if (i < ne) atomicAdd(&ends[edst[i]], 1);
    __syncthreads();
    int v = ends[tid], sc = v;
#pragma unroll
    for (int m = 1; m < 64; m <<= 1) {
        int t = __shfl_up(sc, m);
        if (lane >= m) sc += t;
    }
    if (lane == 63) wpart[wid] = sc;
    __syncthreads();
    if (tid < 16) {
        int s2 = wpart[tid];
#pragma unroll
        for (int m = 1; m < 16; m <<= 1) {
            int t = __shfl_up(s2, m);
            if (tid >= m) s2 += t;
        }
        wpart[tid] = s2;
    }
    __syncthreads();
    int incl = sc + (wid > 0 ? wpart[wid - 1] : 0);
    ends[tid] = incl;
    posc[tid] = incl - v;
    __syncthreads();
#pragma unroll
    for (int i = 0; i < EPT; i++)
        if (i < ne) {
            int p = atomicAdd(&posc[edst[i]], 1);
            csr[p] = ((unsigned)f2bf(eww[i]) << 16) | (unsigned)esrc[i];
        }
    __syncthreads();
    if (tid < N_PER) {
        int s = tid ? ends[tid - 1] : 0, e = ends[tid];
        float s0 = 0.f, s1 = 0.f;
        int k = s;
        for (; k + 2 <= e; k += 2) { s0 += upk(csr[k]); s1 += upk(csr[k + 1]); }
        if (k < e) s0 += upk(csr[k]);
        dl_g[gbase + tid] = rsqrtf(s0 + s1 + 1.0f);
        ends_g[gbase + tid] = e;
    }
    for (int i = tid; i < E_PER; i += 1024)
        csr_g[(size_t)ebase + i] = csr[i];
}

// ===== K2: conv1 gather + W1 + fp8-z; WIDE: 4 blocks/graph x 256 thr ========
__global__ __launch_bounds__(256) void k2_conv1(
    const float* __restrict__ x,
    const float* __restrict__ w1, const float* __restrict__ b1,
    const unsigned* __restrict__ csr_g, const int* __restrict__ ends_g,
    const float* __restrict__ dl_g,
    unsigned char* __restrict__ zg, float* __restrict__ x1g) {
    __shared__ float yl[3000];       // y = dl*x, whole graph
    __shared__ float dls[1000];
    __shared__ float aggv[750];      // own quarter's agg
    __shared__ float sred[4][64];
    int blk = blockIdx.x;
    int g = blk >> 2, qt = blk & 3;
    int tid = threadIdx.x, wid = tid >> 6, lane = tid & 63;
    int gbase = g * N_PER, nbase = qt * 250;
    size_t geb = (size_t)g * E_PER;

    for (int i = tid; i < N_PER; i += 256) dls[i] = dl_g[gbase + i];
    __syncthreads();
    for (int i = tid; i < 3000; i += 256) yl[i] = x[(size_t)gbase * 3 + i] * dls[i / 3];
    __syncthreads();
    if (tid < 250) {
        int n = nbase + tid;
        int s = n ? ends_g[gbase + n - 1] : 0;
        int e = ends_g[gbase + n];
        float a0 = yl[n * 3 + 0], a1 = yl[n * 3 + 1], a2 = yl[n * 3 + 2];
        for (int k = s; k < e; k++) {
            unsigned q = csr_g[geb + k];           // L2-hot (k1 just wrote it)
            int i0 = (int)(q & 0xFFFFu) * 3;
            float wv = upk(q);
            a0 += wv * yl[i0]; a1 += wv * yl[i0 + 1]; a2 += wv * yl[i0 + 2];
        }
        float d = dls[n];
        aggv[tid * 3 + 0] = d * a0;
        aggv[tid * 3 + 1] = d * a1;
        aggv[tid * 3 + 2] = d * a2;
    }
    __syncthreads();
    {
        float w0 = w1[lane], w1v = w1[64 + lane], w2v = w1[128 + lane], bf = b1[lane];
        float px = 0.f;
        int chunk = (lane & 31) >> 3;
        int word  = ((lane >= 32) ? 2 : 0) + ((lane & 7) >> 2);
        unsigned char* zrow = zg + (size_t)g * 64000;
        for (int ln = wid; ln < 250; ln += 4) {
            int node = nbase + ln;
            float a0 = aggv[ln * 3], a1 = aggv[ln * 3 + 1], a2 = aggv[ln * 3 + 2];
            float hv = fmaxf(a0 * w0 + a1 * w1v + a2 * w2v + bf, 0.f);
            px += hv;
            unsigned byte = enc_fp8(dls[node] * hv);
            unsigned t1 = __shfl_xor(byte, 1);
            unsigned v16 = (lane & 1) ? (t1 | (byte << 8)) : (byte | (t1 << 8));
            unsigned t2 = __shfl_xor(v16, 2);
            unsigned v32 = (lane & 2) ? (t2 | (v16 << 16)) : (v16 | (t2 << 16));
            if ((lane & 3) == 0) {
                int cs = chunk ^ ((node >> 1) & 3);
                *(unsigned*)(zrow + node * 64 + cs * 16 + word * 4) = v32;
            }
        }
        sred[wid][lane] = px;
        __syncthreads();
        if (tid < 64) {
            float t = sred[0][tid] + sred[1][tid] + sred[2][tid] + sred[3][tid];
            atomicAdd(&x1g[g * 64 + tid], t * (1.0f / N_PER));
        }
    }
}

// ===== K3: conv2 agg (z LDS) + MFMA + epilogue; 2 blocks/graph ==============
__global__ __launch_bounds__(1024) void k3_conv2(
    const unsigned char* __restrict__ zg, const unsigned* __restrict__ csr_g,
    const int* __restrict__ ends_g, const float* __restrict__ dl_g,
    const float* __restrict__ w2, const float* __restrict__ b2,
    const float* __restrict__ pw,
    unsigned char* __restrict__ h2g, float* __restrict__ score_g) {
    __shared__ __align__(16) unsigned char zs[64000];
    __shared__ unsigned csr[HCAP];
    __shared__ int ends[NH + 12];
    __shared__ float dl[NH + 12];
    __shared__ unsigned short w2s[64 * 64];
    int blk = blockIdx.x;
    int g = blk >> 1, h = blk & 1;
    int tid = threadIdx.x, wid = tid >> 6, lane = tid & 63;
    int kgrp = lane >> 4, nloc = lane & 15;
    int gbase = g * N_PER, nbase = h * NH;

    for (int i = tid; i < 64000 / 4; i += 1024)
        ((unsigned*)zs)[i] = ((const unsigned*)(zg + (size_t)g * 64000))[i];
    int base = h ? ends_g[gbase + NH - 1] : 0;
    int etot = ends_g[gbase + nbase + NH - 1];
    int nE = etot - base;
    if (tid < NH) {
        ends[tid] = ends_g[gbase + nbase + tid] - base;
        dl[tid] = dl_g[gbase + nbase + tid];
    }
    for (int i = tid; i < nE; i += 1024)
        csr[i] = csr_g[(size_t)g * E_PER + base + i];
    {   // w2s[n*64+k] = bf16(w2[k][n])
        int n = tid >> 4;
        for (int k = (tid & 15) * 4, ke = k + 4; k < ke; k++)
            w2s[n * 64 + k] = f2bf(w2[k * 64 + n]);
    }
    float b2c[4], pwc[4];
#pragma unroll
    for (int c = 0; c < 4; ++c) {
        b2c[c] = b2[c * 16 + nloc];
        pwc[c] = pw[c * 16 + nloc];
    }
    float invn;
    {
        float p = pw[lane], pn = p * p;
#pragma unroll
        for (int m = 32; m; m >>= 1) pn += __shfl_xor(pn, m);
        invn = rsqrtf(pn);
    }
    __syncthreads();
#pragma unroll 1
    for (int ti = 0; ti < 2; ti++) {              // 32 tiles cover 500 nodes
        int t = wid + ti * 16;
        int li = t * 16 + nloc;                   // local node in half
        bool valid = li < NH;
        float acc[16];
        int s = 0, cn = 0;
        if (valid) {
            int gn = nbase + li;                  // graph-local node
            uint4 rv = *(const uint4*)(zs + gn * 64 + ((kgrp ^ ((gn >> 1) & 3)) << 4));
#pragma unroll
            for (int j = 0; j < 4; j++) {
                acc[j]      = dec_raw((rv.x >> (8 * j)) & 0x7Fu);
                acc[4 + j]  = dec_raw((rv.y >> (8 * j)) & 0x7Fu);
                acc[8 + j]  = dec_raw((rv.z >> (8 * j)) & 0x7Fu);
                acc[12 + j] = dec_raw((rv.w >> (8 * j)) & 0x7Fu);
            }
            s = li ? ends[li - 1] : 0;
            cn = ends[li] - s;
        } else {
#pragma unroll
            for (int j = 0; j < 16; j++) acc[j] = 0.f;
        }
        int mx = cn;
#pragma unroll
        for (int m = 1; m < 16; m <<= 1) mx = max(mx, __shfl_xor(mx, m));
        for (int k = 0; k < mx; k++) {
            if (k < cn) {
                unsigned q = csr[s + k];
                int src = (int)(q & 0xFFFFu);
                float wv = upk(q);
                uint4 rv = *(const uint4*)(zs + src * 64 + ((kgrp ^ ((src >> 1) & 3)) << 4));
#pragma unroll
                for (int j = 0; j < 4; j++) {
                    acc[j]      += wv * dec_raw((rv.x >> (8 * j)) & 0x7Fu);
                    acc[4 + j]  += wv * dec_raw((rv.y >> (8 * j)) & 0x7Fu);
                    acc[8 + j]  += wv * dec_raw((rv.z >> (8 * j)) & 0x7Fu);
                    acc[12 + j] += wv * dec_raw((rv.w >> (8 * j)) & 0x7Fu);
                }
            }
        }
        float scale = (valid ? dl[li] : 0.f) * 0x1p120f;
        short8 Af0, Af1;
#pragma unroll
        for (int j = 0; j < 8; j++) {
            Af0[j] = (short)f2bf(scale * acc[j]);
            Af1[j] = (short)f2bf(scale * acc[8 + j]);
        }
        float4_ accv[4];
#pragma unroll
        for (int c = 0; c < 4; ++c) {
            const short8* bp = (const short8*)(w2s + (c * 16 + nloc) * 64 + kgrp * 8);
            accv[c] = __builtin_amdgcn_mfma_f32_16x16x32_bf16(Af0, bp[0], (float4_){0.f,0.f,0.f,0.f}, 0, 0, 0);
            accv[c] = __builtin_amdgcn_mfma_f32_16x16x32_bf16(Af1, bp[4], accv[c], 0, 0, 0);
        }
#pragma unroll
        for (int r2 = 0; r2 < 4; ++r2) {
            int li2 = t * 16 + kgrp * 4 + r2;     // C layout: row=(lane>>4)*4+reg
            bool valid2 = li2 < NH;
            float sp = 0.f;
            unsigned pack = 0;
#pragma unroll
            for (int c = 0; c < 4; ++c) {
                float hv = fmaxf(accv[c][r2] + b2c[c], 0.f);
                sp += hv * pwc[c];
                pack |= enc_fp8(hv) << (8 * c);
            }
            if (valid2)
                *(unsigned*)(h2g + (size_t)(gbase + nbase + li2) * 64 + nloc * 4) = pack;
#pragma unroll
            for (int m = 1; m < 16; m <<= 1) sp += __shfl_xor(sp, m);
            if (valid2 && nloc == 0)
                score_g[gbase + nbase + li2] = tanhf(sp * invn);
        }
    }
}

// ===== K4: topk sort + pooled mean + MLP + sigmoid ==========================
__global__ __launch_bounds__(1024) void k4_topk(
    const float* __restrict__ score_g, const unsigned char* __restrict__ h2g,
    const float* __restrict__ x1g,
    const float* __restrict__ l1w, const float* __restrict__ l1b,
    const float* __restrict__ l2w, const float* __restrict__ l2b,
    const float* __restrict__ l3w, const float* __restrict__ l3b,
    float* __restrict__ out) {
    __shared__ unsigned long long keys[1024];
    __shared__ float red[1024];
    __shared__ float zbuf[64], a1buf[64], a2buf[32];
    int b = blockIdx.x, tid = threadIdx.x;
    if (tid < N_PER) {
        float scv = score_g[b * N_PER + tid];
        unsigned bits = __float_as_uint(scv);
        unsigned u = (bits & 0x80000000u) ? ~bits : (bits | 0x80000000u);
        keys[tid] = ((unsigned long long)u << 32) | (unsigned)(1023 - tid);
    } else {
        keys[tid] = 0ull;
    }
    __syncthreads();
    {
        unsigned long long key = keys[tid];
        for (int k = 2; k <= 1024; k <<= 1) {
            for (int j = k >> 1; j > 0; j >>= 1) {
                bool desc = (tid & k) == 0;
                unsigned long long p;
                if (j >= 64) {
                    keys[tid] = key;
                    __syncthreads();
                    p = keys[tid ^ j];
                    __syncthreads();
                } else {
                    p = __shfl_xor(key, j);
                }
                bool low = (tid & j) == 0;
                bool sw = low ? (desc ? (key < p) : (key > p))
                              : (desc ? (p < key) : (p > key));
                if (sw) key = p;
            }
        }
        keys[tid] = key;
    }
    __syncthreads();
    {
        int f = tid & 63, w16 = tid >> 6;
        int boff = ((f & 15) << 2) + (f >> 4);
        float acc2 = 0.f;
        for (int r = w16; r < KSEL; r += 16) {
            unsigned long long key = keys[r];
            int idx = 1023 - (int)(key & 0xFFFFFFFFu);
            unsigned u = (unsigned)(key >> 32);
            unsigned bits = (u & 0x80000000u) ? (u & 0x7FFFFFFFu) : ~u;
            float valS = __uint_as_float(bits) * 0x1p120f;
            acc2 += valS * dec_raw((unsigned)h2g[(size_t)(b * N_PER + idx) * 64 + boff] & 0x7Fu);
        }
        red[tid] = acc2;
    }
    __syncthreads();
    if (tid < 64) {
        float s2 = 0.f;
        for (int ww = 0; ww < 16; ww++) s2 += red[ww * 64 + tid];
        zbuf[tid] = x1g[b * 64 + tid] + s2 * (1.0f / KSEL);
    }
    __syncthreads();
    if (tid < 64) {
        float a = l1b[tid];
        for (int k = 0; k < 64; k++) a += zbuf[k] * l1w[k * 64 + tid];
        a1buf[tid] = fmaxf(a, 0.f);
    }
    __syncthreads();
    if (tid < 32) {
        float a = l2b[tid];
        for (int k = 0; k < 64; k++) a += a1buf[k] * l2w[k * 32 + tid];
        a2buf[tid] = fmaxf(a, 0.f);
    }
    __syncthreads();
    if (tid == 0) {
        float t = l3b[0];
        for (int k = 0; k < 32; k++) t += a2buf[k] * l3w[k];
        out[b] = 1.0f / (1.0f + expf(-t));
    }
}

extern "C" void kernel_launch(void* const* d_in, const int* in_sizes, int n_in,
                              void* d_out, int out_size, void* d_ws, size_t ws_size,
                              hipStream_t stream) {
    const float* x   = (const float*)d_in[0];
    const int*   ei  = (const int*)d_in[1];
    const float* ew  = (const float*)d_in[2];
    const float* c1w = (const float*)d_in[4];
    const float* c1b = (const float*)d_in[5];
    const float* c2w = (const float*)d_in[6];
    const float* c2b = (const float*)d_in[7];
    const float* pw  = (const float*)d_in[8];
    const float* l1w = (const float*)d_in[9];
    const float* l1b = (const float*)d_in[10];
    const float* l2w = (const float*)d_in[11];
    const float* l2b = (const float*)d_in[12];
    const float* l3w = (const float*)d_in[13];
    const float* l3b = (const float*)d_in[14];
    float* out = (float*)d_out;

    char* ws = (char*)d_ws;
    size_t o = 0;
    auto alloc = [&](size_t bytes) { size_t cur = o; o += (bytes + 511) & ~(size_t)511; return cur; };
    unsigned*      csr_g   = (unsigned*)(ws + alloc((size_t)ETOT * 4));       // 4.8 MB
    unsigned char* zg      = (unsigned char*)(ws + alloc((size_t)NTOT * 64)); // 6.4 MB
    unsigned char* h2g     = (unsigned char*)(ws + alloc((size_t)NTOT * 64)); // 6.4 MB
    int*           ends_g  = (int*)(ws + alloc((size_t)NTOT * 4));
    float*         dl_g    = (float*)(ws + alloc((size_t)NTOT * 4));
    float*         score_g = (float*)(ws + alloc((size_t)NTOT * 4));
    float*         x1g     = (float*)(ws + alloc((size_t)B_G * 64 * 4));
    (void)ws_size; (void)in_sizes; (void)n_in; (void)out_size;

    k1_build<<<B_G, 1024, 0, stream>>>(ei, ew, csr_g, ends_g, dl_g, x1g);
    k2_conv1<<<B_G * 4, 256, 0, stream>>>(x, c1w, c1b, csr_g, ends_g, dl_g, zg, x1g);
    k3_conv2<<<B_G * 2, 1024, 0, stream>>>(zg, csr_g, ends_g, dl_g, c2w, c2b, pw, h2g, score_g);
    k4_topk <<<B_G, 1024, 0, stream>>>(score_g, h2g, x1g, l1w, l1b, l2w, l2b, l3w, l3b, out);
}

// Round 14
// 185.415 us; speedup vs baseline: 1.0389x; 1.0049x over previous
//
#include <hip/hip_runtime.h>

#define B_G   100
#define N_PER 1000
#define E_PER 12000
#define NTOT  (B_G * N_PER)
#define ETOT  (B_G * E_PER)
#define KSEL  800
#define EPT   12
#define NH    500            // nodes per half
#define CAPH  8192           // per (graph,half) csr region capacity

typedef __attribute__((ext_vector_type(8))) short short8;
typedef __attribute__((ext_vector_type(4))) float float4_;

__device__ __forceinline__ unsigned short f2bf(float f) {
    unsigned u = __float_as_uint(f);
    u += 0x7fffu + ((u >> 16) & 1u);          // RNE
    return (unsigned short)(u >> 16);
}
__device__ __forceinline__ float upk(unsigned q) {          // bf16 ew in hi16
    return __uint_as_float(q & 0xFFFF0000u);
}
// fp8 e4m3 (z>=0) for h2 only: raw decode = value * 2^-120
__device__ __forceinline__ float dec_raw(unsigned byte7f) {
    return __uint_as_float(byte7f << 20);
}
__device__ __forceinline__ unsigned enc_fp8(float z) {
    unsigned u = __float_as_uint(z * 0x1p-120f);
    u += 0x7FFFFu + ((u >> 20) & 1u);
    return u >> 20;
}

// ===== K1: per-HALF build (2 blocks/graph): hist + scan + fill + dl =========
__global__ __launch_bounds__(1024) void k1_build(
    const int* __restrict__ ei, const float* __restrict__ ew,
    unsigned* __restrict__ csr_g, int* __restrict__ ends_g,
    float* __restrict__ dl_g) {
    __shared__ unsigned csr[CAPH];
    __shared__ int ends[1024];
    __shared__ int posc[1024];
    __shared__ int wpart[16];
    int blk = blockIdx.x;
    int g = blk >> 1, h = blk & 1;
    int tid = threadIdx.x, wid = tid >> 6, lane = tid & 63;
    int gbase = g * N_PER, ebase = g * E_PER;
    int nb0 = h * NH;

    int esrc[EPT], edst[EPT]; float eww[EPT];
    int ne = (tid < (E_PER - (EPT - 1) * 1024)) ? EPT : EPT - 1;
#pragma unroll
    for (int i = 0; i < EPT; i++) {
        if (i < ne) {
            int e = tid + i * 1024;
            esrc[i] = ei[ebase + e] - gbase;
            edst[i] = ei[ETOT + ebase + e] - gbase - nb0;   // local to half
            eww[i]  = ew[ebase + e];
        }
    }
    ends[tid] = 0;
    __syncthreads();
#pragma unroll
    for (int i = 0; i < EPT; i++)
        if (i < ne && (unsigned)edst[i] < NH) atomicAdd(&ends[edst[i]], 1);
    __syncthreads();
    int v = ends[tid], sc = v;
#pragma unroll
    for (int m = 1; m < 64; m <<= 1) {
        int t = __shfl_up(sc, m);
        if (lane >= m) sc += t;
    }
    if (lane == 63) wpart[wid] = sc;
    __syncthreads();
    if (tid < 16) {
        int s2 = wpart[tid];
#pragma unroll
        for (int m = 1; m < 16; m <<= 1) {
            int t = __shfl_up(s2, m);
            if (tid >= m) s2 += t;
        }
        wpart[tid] = s2;
    }
    __syncthreads();
    int incl = sc + (wid > 0 ? wpart[wid - 1] : 0);
    ends[tid] = incl;
    posc[tid] = incl - v;
    __syncthreads();
#pragma unroll
    for (int i = 0; i < EPT; i++)
        if (i < ne && (unsigned)edst[i] < NH) {
            int p = atomicAdd(&posc[edst[i]], 1);
            if (p < CAPH)
                csr[p] = ((unsigned)f2bf(eww[i]) << 16) | (unsigned)esrc[i];
        }
    __syncthreads();
    if (tid < NH) {
        int s = tid ? ends[tid - 1] : 0, e = ends[tid];
        float s0 = 0.f, s1 = 0.f;
        int k = s;
        for (; k + 2 <= e; k += 2) { s0 += upk(csr[k]); s1 += upk(csr[k + 1]); }
        if (k < e) s0 += upk(csr[k]);
        dl_g[gbase + nb0 + tid] = rsqrtf(s0 + s1 + 1.0f);
        ends_g[gbase + nb0 + tid] = e;               // LOCAL (region) offsets
    }
    int nE = ends[NH - 1];
    for (int i = tid; i < nE; i += 1024)
        csr_g[(size_t)blk * CAPH + i] = csr[i];
}

// ===== K2: conv1 gather + W1 + zmax + linear-u8 z; 1 block/graph ============
__global__ __launch_bounds__(1024) void k2_conv1(
    const float* __restrict__ x,
    const float* __restrict__ w1, const float* __restrict__ b1,
    const unsigned* __restrict__ csr_g, const int* __restrict__ ends_g,
    const float* __restrict__ dl_g,
    unsigned char* __restrict__ zg, float* __restrict__ x1g,
    float* __restrict__ zscale_g) {
    __shared__ float yl[3000];
    __shared__ float dls[1000];
    __shared__ float aggv[3000];
    __shared__ float sred[1024];
    __shared__ float zmaxs;
    int g = blockIdx.x, tid = threadIdx.x;
    int wid = tid >> 6, lane = tid & 63;
    int gbase = g * N_PER;

    for (int i = tid; i < 1000; i += 1024) dls[i] = dl_g[gbase + i];
    __syncthreads();
    for (int i = tid; i < 3000; i += 1024) yl[i] = x[(size_t)gbase * 3 + i] * dls[i / 3];
    __syncthreads();
    if (tid < 1000) {
        int h = tid >= NH;
        int loc = tid - h * NH;
        size_t rb = ((size_t)g * 2 + h) * CAPH;
        int s = loc ? ends_g[gbase + tid - 1] : 0;
        int e = ends_g[gbase + tid];
        float a0 = yl[tid * 3 + 0], a1 = yl[tid * 3 + 1], a2 = yl[tid * 3 + 2];
        for (int k = s; k < e; k++) {
            unsigned q = csr_g[rb + k];            // L2-hot (k1 just wrote it)
            int i0 = (int)(q & 0xFFFFu) * 3;
            float wv = upk(q);
            a0 += wv * yl[i0]; a1 += wv * yl[i0 + 1]; a2 += wv * yl[i0 + 2];
        }
        float d = dls[tid];
        aggv[tid * 3 + 0] = d * a0;
        aggv[tid * 3 + 1] = d * a1;
        aggv[tid * 3 + 2] = d * a2;
    }
    __syncthreads();
    float w0 = w1[lane], w1v = w1[64 + lane], w2v = w1[128 + lane], bf = b1[lane];
    // pass 1: x1 partials + zmax
    {
        float px = 0.f, zmx = 0.f;
        for (int node = wid; node < 1000; node += 16) {
            float a0 = aggv[node * 3], a1 = aggv[node * 3 + 1], a2 = aggv[node * 3 + 2];
            float hv = fmaxf(a0 * w0 + a1 * w1v + a2 * w2v + bf, 0.f);
            px += hv;
            zmx = fmaxf(zmx, dls[node] * hv);
        }
        sred[tid] = px;
        __syncthreads();
        if (tid < 64) {
            float t = 0.f;
            for (int r = 0; r < 16; r++) t += sred[r * 64 + tid];
            x1g[g * 64 + tid] = t * (1.0f / N_PER);
        }
        __syncthreads();
        sred[tid] = zmx;
        __syncthreads();
        if (tid < 64) {
            float m = sred[tid];
            for (int r = 1; r < 16; r++) m = fmaxf(m, sred[r * 64 + tid]);
#pragma unroll
            for (int off = 32; off; off >>= 1) m = fmaxf(m, __shfl_xor(m, off));
            if (tid == 0) {
                zmaxs = m;
                zscale_g[g] = m * (1.0f / 255.0f);
            }
        }
        __syncthreads();
    }
    // pass 2: encode z as linear u8 (chunk-swizzled layout, same as before)
    {
        float s255 = (zmaxs > 0.f) ? 255.0f / zmaxs : 0.f;
        int chunk = (lane & 31) >> 3;
        int word  = ((lane >= 32) ? 2 : 0) + ((lane & 7) >> 2);
        unsigned char* zrow = zg + (size_t)g * 64000;
        for (int node = wid; node < 1000; node += 16) {
            float a0 = aggv[node * 3], a1 = aggv[node * 3 + 1], a2 = aggv[node * 3 + 2];
            float hv = fmaxf(a0 * w0 + a1 * w1v + a2 * w2v + bf, 0.f);
            float zq = dls[node] * hv * s255 + 0.5f;
            unsigned byte = (unsigned)fminf(zq, 255.f);
            unsigned t1 = __shfl_xor(byte, 1);
            unsigned v16 = (lane & 1) ? (t1 | (byte << 8)) : (byte | (t1 << 8));
            unsigned t2 = __shfl_xor(v16, 2);
            unsigned v32 = (lane & 2) ? (t2 | (v16 << 16)) : (v16 | (t2 << 16));
            if ((lane & 3) == 0) {
                int cs = chunk ^ ((node >> 1) & 3);
                *(unsigned*)(zrow + node * 64 + cs * 16 + word * 4) = v32;
            }
        }
    }
}

// ===== K3: conv2 agg (u8 z, cvt_f32_ubyte decode) + MFMA; 2 blocks/graph ====
__global__ __launch_bounds__(1024) void k3_conv2(
    const unsigned char* __restrict__ zg, const unsigned* __restrict__ csr_g,
    const int* __restrict__ ends_g, const float* __restrict__ dl_g,
    const float* __restrict__ zscale_g,
    const float* __restrict__ w2, const float* __restrict__ b2,
    const float* __restrict__ pw,
    unsigned char* __restrict__ h2g, float* __restrict__ score_g) {
    __shared__ __align__(16) unsigned char zs[64000];
    __shared__ unsigned csr[CAPH];
    __shared__ int ends[NH];
    __shared__ float dl[NH];
    __shared__ unsigned short w2s[64 * 64];
    int blk = blockIdx.x;
    int g = blk >> 1, h = blk & 1;
    int tid = threadIdx.x, wid = tid >> 6, lane = tid & 63;
    int kgrp = lane >> 4, nloc = lane & 15;
    int gbase = g * N_PER, nbase = h * NH;

    for (int i = tid; i < 64000 / 4; i += 1024)
        ((unsigned*)zs)[i] = ((const unsigned*)(zg + (size_t)g * 64000))[i];
    int nE = ends_g[gbase + nbase + NH - 1];
    if (tid < NH) {
        ends[tid] = ends_g[gbase + nbase + tid];
        dl[tid] = dl_g[gbase + nbase + tid];
    }
    for (int i = tid; i < nE; i += 1024)
        csr[i] = csr_g[((size_t)g * 2 + h) * CAPH + i];
    {   // w2s[n*64+k] = bf16(w2[k][n])
        int n = tid >> 4;
        for (int k = (tid & 15) * 4, ke = k + 4; k < ke; k++)
            w2s[n * 64 + k] = f2bf(w2[k * 64 + n]);
    }
    float b2c[4], pwc[4];
#pragma unroll
    for (int c = 0; c < 4; ++c) {
        b2c[c] = b2[c * 16 + nloc];
        pwc[c] = pw[c * 16 + nloc];
    }
    float invn;
    {
        float p = pw[lane], pn = p * p;
#pragma unroll
        for (int m = 32; m; m >>= 1) pn += __shfl_xor(pn, m);
        invn = rsqrtf(pn);
    }
    float zsc = zscale_g[g];
    __syncthreads();
#pragma unroll 1
    for (int ti = 0; ti < 2; ti++) {              // 32 tiles cover 500 nodes
        int t = wid + ti * 16;
        int li = t * 16 + nloc;
        bool valid = li < NH;
        float acc[16];
        int s = 0, cn = 0;
        if (valid) {
            int gn = nbase + li;
            uint4 rv = *(const uint4*)(zs + gn * 64 + ((kgrp ^ ((gn >> 1) & 3)) << 4));
#pragma unroll
            for (int j = 0; j < 4; j++) {         // v_cvt_f32_ubyteN pattern
                acc[j]      = (float)((rv.x >> (8 * j)) & 0xFFu);
                acc[4 + j]  = (float)((rv.y >> (8 * j)) & 0xFFu);
                acc[8 + j]  = (float)((rv.z >> (8 * j)) & 0xFFu);
                acc[12 + j] = (float)((rv.w >> (8 * j)) & 0xFFu);
            }
            s = li ? ends[li - 1] : 0;
            cn = ends[li] - s;
        } else {
#pragma unroll
            for (int j = 0; j < 16; j++) acc[j] = 0.f;
        }
        int mx = cn;
#pragma unroll
        for (int m = 1; m < 16; m <<= 1) mx = max(mx, __shfl_xor(mx, m));
        for (int k = 0; k < mx; k++) {
            if (k < cn) {
                unsigned q = csr[s + k];
                int src = (int)(q & 0xFFFFu);
                float wv = upk(q);
                uint4 rv = *(const uint4*)(zs + src * 64 + ((kgrp ^ ((src >> 1) & 3)) << 4));
#pragma unroll
                for (int j = 0; j < 4; j++) {
                    acc[j]      += wv * (float)((rv.x >> (8 * j)) & 0xFFu);
                    acc[4 + j]  += wv * (float)((rv.y >> (8 * j)) & 0xFFu);
                    acc[8 + j]  += wv * (float)((rv.z >> (8 * j)) & 0xFFu);
                    acc[12 + j] += wv * (float)((rv.w >> (8 * j)) & 0xFFu);
                }
            }
        }
        float scale = (valid ? dl[li] : 0.f) * zsc;
        short8 Af0, Af1;
#pragma unroll
        for (int j = 0; j < 8; j++) {
            Af0[j] = (short)f2bf(scale * acc[j]);
            Af1[j] = (short)f2bf(scale * acc[8 + j]);
        }
        float4_ accv[4];
#pragma unroll
        for (int c = 0; c < 4; ++c) {
            const short8* bp = (const short8*)(w2s + (c * 16 + nloc) * 64 + kgrp * 8);
            accv[c] = __builtin_amdgcn_mfma_f32_16x16x32_bf16(Af0, bp[0], (float4_){0.f,0.f,0.f,0.f}, 0, 0, 0);
            accv[c] = __builtin_amdgcn_mfma_f32_16x16x32_bf16(Af1, bp[4], accv[c], 0, 0, 0);
        }
#pragma unroll
        for (int r2 = 0; r2 < 4; ++r2) {
            int li2 = t * 16 + kgrp * 4 + r2;     // C layout: row=(lane>>4)*4+reg
            bool valid2 = li2 < NH;
            float sp = 0.f;
            unsigned pack = 0;
#pragma unroll
            for (int c = 0; c < 4; ++c) {
                float hv = fmaxf(accv[c][r2] + b2c[c], 0.f);
                sp += hv * pwc[c];
                pack |= enc_fp8(hv) << (8 * c);
            }
            if (valid2)
                *(unsigned*)(h2g + (size_t)(gbase + nbase + li2) * 64 + nloc * 4) = pack;
#pragma unroll
            for (int m = 1; m < 16; m <<= 1) sp += __shfl_xor(sp, m);
            if (valid2 && nloc == 0)
                score_g[gbase + nbase + li2] = tanhf(sp * invn);
        }
    }
}

// ===== K4: topk sort + pooled mean + MLP + sigmoid ==========================
__global__ __launch_bounds__(1024) void k4_topk(
    const float* __restrict__ score_g, const unsigned char* __restrict__ h2g,
    const float* __restrict__ x1g,
    const float* __restrict__ l1w, const float* __restrict__ l1b,
    const float* __restrict__ l2w, const float* __restrict__ l2b,
    const float* __restrict__ l3w, const float* __restrict__ l3b,
    float* __restrict__ out) {
    __shared__ unsigned long long keys[1024];
    __shared__ float red[1024];
    __shared__ float zbuf[64], a1buf[64], a2buf[32];
    int b = blockIdx.x, tid = threadIdx.x;
    if (tid < N_PER) {
        float scv = score_g[b * N_PER + tid];
        unsigned bits = __float_as_uint(scv);
        unsigned u = (bits & 0x80000000u) ? ~bits : (bits | 0x80000000u);
        keys[tid] = ((unsigned long long)u << 32) | (unsigned)(1023 - tid);
    } else {
        keys[tid] = 0ull;
    }
    __syncthreads();
    {
        unsigned long long key = keys[tid];
        for (int k = 2; k <= 1024; k <<= 1) {
            for (int j = k >> 1; j > 0; j >>= 1) {
                bool desc = (tid & k) == 0;
                unsigned long long p;
                if (j >= 64) {
                    keys[tid] = key;
                    __syncthreads();
                    p = keys[tid ^ j];
                    __syncthreads();
                } else {
                    p = __shfl_xor(key, j);
                }
                bool low = (tid & j) == 0;
                bool sw = low ? (desc ? (key < p) : (key > p))
                              : (desc ? (p < key) : (p > key));
                if (sw) key = p;
            }
        }
        keys[tid] = key;
    }
    __syncthreads();
    {
        int f = tid & 63, w16 = tid >> 6;
        int boff = ((f & 15) << 2) + (f >> 4);
        float acc2 = 0.f;
        for (int r = w16; r < KSEL; r += 16) {
            unsigned long long key = keys[r];
            int idx = 1023 - (int)(key & 0xFFFFFFFFu);
            unsigned u = (unsigned)(key >> 32);
            unsigned bits = (u & 0x80000000u) ? (u & 0x7FFFFFFFu) : ~u;
            float valS = __uint_as_float(bits) * 0x1p120f;
            acc2 += valS * dec_raw((unsigned)h2g[(size_t)(b * N_PER + idx) * 64 + boff] & 0x7Fu);
        }
        red[tid] = acc2;
    }
    __syncthreads();
    if (tid < 64) {
        float s2 = 0.f;
        for (int ww = 0; ww < 16; ww++) s2 += red[ww * 64 + tid];
        zbuf[tid] = x1g[b * 64 + tid] + s2 * (1.0f / KSEL);
    }
    __syncthreads();
    if (tid < 64) {
        float a = l1b[tid];
        for (int k = 0; k < 64; k++) a += zbuf[k] * l1w[k * 64 + tid];
        a1buf[tid] = fmaxf(a, 0.f);
    }
    __syncthreads();
    if (tid < 32) {
        float a = l2b[tid];
        for (int k = 0; k < 64; k++) a += a1buf[k] * l2w[k * 32 + tid];
        a2buf[tid] = fmaxf(a, 0.f);
    }
    __syncthreads();
    if (tid == 0) {
        float t = l3b[0];
        for (int k = 0; k < 32; k++) t += a2buf[k] * l3w[k];
        out[b] = 1.0f / (1.0f + expf(-t));
    }
}

extern "C" void kernel_launch(void* const* d_in, const int* in_sizes, int n_in,
                              void* d_out, int out_size, void* d_ws, size_t ws_size,
                              hipStream_t stream) {
    const float* x   = (const float*)d_in[0];
    const int*   ei  = (const int*)d_in[1];
    const float* ew  = (const float*)d_in[2];
    const float* c1w = (const float*)d_in[4];
    const float* c1b = (const float*)d_in[5];
    const float* c2w = (const float*)d_in[6];
    const float* c2b = (const float*)d_in[7];
    const float* pw  = (const float*)d_in[8];
    const float* l1w = (const float*)d_in[9];
    const float* l1b = (const float*)d_in[10];
    const float* l2w = (const float*)d_in[11];
    const float* l2b = (const float*)d_in[12];
    const float* l3w = (const float*)d_in[13];
    const float* l3b = (const float*)d_in[14];
    float* out = (float*)d_out;

    char* ws = (char*)d_ws;
    size_t o = 0;
    auto alloc = [&](size_t bytes) { size_t cur = o; o += (bytes + 511) & ~(size_t)511; return cur; };
    unsigned*      csr_g    = (unsigned*)(ws + alloc((size_t)B_G * 2 * CAPH * 4)); // 6.6 MB
    unsigned char* zg       = (unsigned char*)(ws + alloc((size_t)NTOT * 64));     // 6.4 MB
    unsigned char* h2g      = (unsigned char*)(ws + alloc((size_t)NTOT * 64));     // 6.4 MB
    int*           ends_g   = (int*)(ws + alloc((size_t)NTOT * 4));
    float*         dl_g     = (float*)(ws + alloc((size_t)NTOT * 4));
    float*         score_g  = (float*)(ws + alloc((size_t)NTOT * 4));
    float*         x1g      = (float*)(ws + alloc((size_t)B_G * 64 * 4));
    float*         zscale_g = (float*)(ws + alloc((size_t)B_G * 4));
    (void)ws_size; (void)in_sizes; (void)n_in; (void)out_size;

    k1_build<<<B_G * 2, 1024, 0, stream>>>(ei, ew, csr_g, ends_g, dl_g);
    k2_conv1<<<B_G, 1024, 0, stream>>>(x, c1w, c1b, csr_g, ends_g, dl_g, zg, x1g, zscale_g);
    k3_conv2<<<B_G * 2, 1024, 0, stream>>>(zg, csr_g, ends_g, dl_g, zscale_g, c2w, c2b, pw, h2g, score_g);
    k4_topk <<<B_G, 1024, 0, stream>>>(score_g, h2g, x1g, l1w, l1b, l2w, l2b, l3w, l3b, out);
}